// Round 2
// baseline (133.538 us; speedup 1.0000x reference)
//
#include <hip/hip_runtime.h>

// FlowGNN: 2-layer temporal GNN, fused single kernel.
// Reference shapes: N=100000, D=32, B=2048, F_IN=64, F_H=128, F_OUT=64.
#define DEG   32
#define F_IN  64
#define F_H   128
#define F_OUT 64
#define NW    8            // waves per block
#define BLOCK (NW * 64)

__launch_bounds__(BLOCK, 4)
__global__ void flowgnn_kernel(const float* __restrict__ x,
                               const float* __restrict__ times,
                               const float* __restrict__ ts,
                               const float* __restrict__ W0,
                               const float* __restrict__ b0,
                               const float* __restrict__ W1,
                               const float* __restrict__ b1,
                               const int*   __restrict__ batch,
                               const int*   __restrict__ idx,
                               float*       __restrict__ out)
{
    __shared__ __align__(16) float W0s[F_IN * F_H];   // 32 KB staged W0
    __shared__ float t2_s[DEG + 1];                   // frontier query times (t2_s[32] = times[b])
    __shared__ int   nodes_s[DEG + 1];                // frontier node ids   (nodes_s[32] = batch[b])
    __shared__ __align__(16) float meanw[NW * F_IN];  // per-wave mean broadcast
    __shared__ __align__(16) float red[NW * F_H];     // cross-wave agg1 partials
    __shared__ __align__(16) float aggm[F_H];         // agg1 / cnt1

    const int b    = blockIdx.x;
    const int t    = threadIdx.x;
    const int wid  = t >> 6;
    const int lane = t & 63;

    const int   node0 = batch[b];
    const float tb    = times[b];

    // ---- stage W0 into LDS (coalesced float4) ----
    {
        const float4* src = (const float4*)W0;
        float4*       dst = (float4*)W0s;
        #pragma unroll
        for (int i = t; i < (F_IN * F_H) / 4; i += BLOCK) dst[i] = src[i];
    }
    // ---- layer-2 frontier metadata ----
    if (t < DEG) {
        t2_s[t]    = ts [node0 * DEG + t];
        nodes_s[t] = idx[node0 * DEG + t];
    }
    if (t == DEG) {            // self-loop entry
        t2_s[DEG]    = tb;
        nodes_s[DEG] = node0;
    }
    __syncthreads();

    // lane owns h1 channels (2*lane, 2*lane+1)
    const float b0x = b0[2 * lane];
    const float b0y = b0[2 * lane + 1];
    float a1x = 0.f, a1y = 0.f;

    // ---- each wave independently processes frontier nodes j = wid, wid+NW, ... ----
    for (int j = wid; j <= DEG; j += NW) {
        const float tq = t2_s[j];
        if (!(tq <= tb)) continue;        // mask_full[j]==0: whole h1_j dead (exec-uniform skip)

        const int node = nodes_s[j];
        const int l32  = lane & 31;
        const int   nb = idx[node * DEG + l32];   // lanes 32..63 duplicate 0..31 (same cachelines)
        const float tn = ts [node * DEG + l32];

        float acc = x[node * F_IN + lane];        // self-loop feature (issued early)

        const unsigned long long bal = __ballot(tn <= tq);
        const unsigned ms = __builtin_amdgcn_readfirstlane((unsigned)(bal & 0xffffffffULL));
        const float cntf = (float)(__popc(ms) + 1);

        // Masked gather with SCALAR branch skip + deferred adds:
        // loads cluster inside branch bodies (no uses -> no per-load waits);
        // the accumulate after the group takes one conservative vmcnt wait.
        #pragma unroll
        for (int g = 0; g < 2; ++g) {
            float v[16];
            #pragma unroll
            for (int n = 0; n < 16; ++n) {
                v[n] = 0.f;
                const int r = g * 16 + n;
                if (ms & (1u << r)) {                       // wave-uniform scalar test
                    const int nbr = __builtin_amdgcn_readlane(nb, r);
                    v[n] = x[nbr * F_IN + lane];            // saddr-form coalesced 256B row
                }
            }
            #pragma unroll
            for (int n = 0; n < 16; ++n) acc += v[n];       // masked rows add +0.0 (same order as ref)
        }
        const float mean = acc / cntf;            // matches reference agg0/cnt0

        // broadcast mean across the wave via per-wave LDS slice (same-wave, in-order LDS)
        meanw[wid * F_IN + lane] = mean;

        float hx = 0.f, hy = 0.f;
        #pragma unroll
        for (int f4 = 0; f4 < F_IN / 4; ++f4) {
            const float4 m4 = *(const float4*)&meanw[wid * F_IN + 4 * f4];
            const float2 wa = *(const float2*)&W0s[(4 * f4 + 0) * F_H + 2 * lane];
            const float2 wb = *(const float2*)&W0s[(4 * f4 + 1) * F_H + 2 * lane];
            const float2 wc = *(const float2*)&W0s[(4 * f4 + 2) * F_H + 2 * lane];
            const float2 wd = *(const float2*)&W0s[(4 * f4 + 3) * F_H + 2 * lane];
            hx += m4.x * wa.x; hy += m4.x * wa.y;
            hx += m4.y * wb.x; hy += m4.y * wb.y;
            hx += m4.z * wc.x; hy += m4.z * wc.y;
            hx += m4.w * wd.x; hy += m4.w * wd.y;
        }
        a1x += fmaxf(hx + b0x, 0.f);              // relu(h1) accumulated into agg1 partial
        a1y += fmaxf(hy + b0y, 0.f);
    }

    // ---- cross-wave reduction of agg1 ----
    red[wid * F_H + 2 * lane]     = a1x;
    red[wid * F_H + 2 * lane + 1] = a1y;
    __syncthreads();

    if (wid == 0) {
        bool mf = false;
        if (lane <= DEG) mf = (t2_s[lane] <= tb);
        const float cnt1 = (float)__popcll(__ballot(mf));

        float sx = 0.f, sy = 0.f;
        #pragma unroll
        for (int w = 0; w < NW; ++w) {
            sx += red[w * F_H + 2 * lane];
            sy += red[w * F_H + 2 * lane + 1];
        }
        aggm[2 * lane]     = sx / cnt1;
        aggm[2 * lane + 1] = sy / cnt1;
        // same-wave LDS write->read: ordered by in-order LDS pipe + compiler lgkmcnt

        // ---- GEMM2: out[c] = relu(aggm . W1[:,c] + b1[c]), lane = c ----
        float o = b1[lane];
        #pragma unroll
        for (int k4 = 0; k4 < F_H / 4; ++k4) {
            const float4 a4 = *(const float4*)&aggm[4 * k4];
            o += a4.x * W1[(4 * k4 + 0) * F_OUT + lane];
            o += a4.y * W1[(4 * k4 + 1) * F_OUT + lane];
            o += a4.z * W1[(4 * k4 + 2) * F_OUT + lane];
            o += a4.w * W1[(4 * k4 + 3) * F_OUT + lane];
        }
        out[b * F_OUT + lane] = fmaxf(o, 0.f);
    }
}

extern "C" void kernel_launch(void* const* d_in, const int* in_sizes, int n_in,
                              void* d_out, int out_size, void* d_ws, size_t ws_size,
                              hipStream_t stream)
{
    const float* x     = (const float*)d_in[0];
    const float* times = (const float*)d_in[1];
    const float* ts    = (const float*)d_in[2];
    const float* W0    = (const float*)d_in[3];
    const float* b0    = (const float*)d_in[4];
    const float* W1    = (const float*)d_in[5];
    const float* b1    = (const float*)d_in[6];
    const int*   batch = (const int*)d_in[7];
    const int*   idx   = (const int*)d_in[8];
    float*       out   = (float*)d_out;

    const int B = in_sizes[1];   // 2048 queries
    flowgnn_kernel<<<B, BLOCK, 0, stream>>>(x, times, ts, W0, b0, W1, b1, batch, idx, out);
}